// Round 5
// baseline (152.556 us; speedup 1.0000x reference)
//
#include <hip/hip_runtime.h>
#include <hip/hip_bf16.h>
#include <stdint.h>

#define MARGIN   0.5f
#define POS_THR  (1.0f - 1e-5f)

typedef __attribute__((ext_vector_type(8))) short  short8;
typedef __attribute__((ext_vector_type(4))) float  f32x4;

#define BM 128
#define BN 128
#define BK 32
#define NPANEL_SHIFT 7   // BN = 128
#define NSLOTS 256       // misc[0..255] partial sums, misc[256] = stale pos

// ---------- helpers ----------
__device__ __forceinline__ ushort f2bf_rne(float x) {
  uint32_t u = __float_as_uint(x);
  u += 0x7fffu + ((u >> 16) & 1u);
  return (ushort)(u >> 16);
}

__device__ __forceinline__ void async_load16(const ushort* g, ushort* l) {
  // width-16 global->LDS DMA; LDS dest = wave-uniform base + lane*16B
  __builtin_amdgcn_global_load_lds(
      (__attribute__((address_space(1))) void*)(const_cast<ushort*>(g)),
      (__attribute__((address_space(3))) void*)(l),
      16, 0, 0);
}

// ---------- prep: f32->bf16 convert (8-wide) + zero cnt/flags/misc ----------
__global__ void prep_kernel(const float* __restrict__ src, ushort* __restrict__ dst,
                            int* __restrict__ cnt, int* __restrict__ flags,
                            float* __restrict__ misc, int total8, int n, int npanel) {
  int i = blockIdx.x * blockDim.x + threadIdx.x;
  if (i < total8) {
    const float4* s4 = reinterpret_cast<const float4*>(src);
    float4 a = s4[i * 2], b = s4[i * 2 + 1];
    short8 o;
    o[0] = (short)f2bf_rne(a.x); o[1] = (short)f2bf_rne(a.y);
    o[2] = (short)f2bf_rne(a.z); o[3] = (short)f2bf_rne(a.w);
    o[4] = (short)f2bf_rne(b.x); o[5] = (short)f2bf_rne(b.y);
    o[6] = (short)f2bf_rne(b.z); o[7] = (short)f2bf_rne(b.w);
    reinterpret_cast<short8*>(dst)[i] = o;
  }
  if (i < n) cnt[i] = 0;
  if (i < npanel) flags[i] = 0;
  if (i < NSLOTS + 1) misc[i] = 0.f;
}

// ---------- count: histogram new_idx + per-col-panel has-new flags ----------
__global__ void count_kernel(const int* __restrict__ new_idx, int* __restrict__ cnt,
                             int* __restrict__ flags, int n_new) {
  int i = blockIdx.x * blockDim.x + threadIdx.x;
  if (i < n_new) {
    int idx = new_idx[i];
    atomicAdd(&cnt[idx], 1);
    atomicOr(&flags[idx >> NPANEL_SHIFT], 1);
  }
}

// ---------- main fused GEMM + masked-reduction ----------
// sim = F*F^T (bf16 MFMA 16x16x32, fp32 accum), 128x128 tile, 4 waves (2x2),
// 3-buffer ring: counted vmcnt(4) + one raw s_barrier per kstep. NO manual
// lgkmcnt drain — native ds_reads let the compiler emit fine-grained
// lgkmcnt(N) interleaved with MFMAs (m97 evidence; forced drain = m141 trap).
// Everything except stale=pos[n_new-1] is linear -> per-block scalar reduce.
__global__ __launch_bounds__(256) void simloss_kernel(
    const ushort* __restrict__ fb, const int* __restrict__ target,
    const int* __restrict__ cnt, const int* __restrict__ colHasNew,
    float* __restrict__ misc, int d, int n_new, float alpha) {
  __shared__ __align__(16) ushort Als[3][BM * BK];
  __shared__ __align__(16) ushort Bls[3][BN * BK];
  __shared__ int   t_row[BM];
  __shared__ int   t_col[BN];
  __shared__ float cw_col[BN];
  __shared__ float red[4];

  const int tid = threadIdx.x;
  const int rowBase = blockIdx.y * BM;
  const int colBase = blockIdx.x * BN;

  // old-row block over a panel with no new cols: contributes nothing
  if (rowBase >= n_new && colHasNew[blockIdx.x] == 0) return;

  if (tid < BM) t_row[tid] = target[rowBase + tid];
  if (tid < BN) {
    t_col[tid]  = target[colBase + tid];
    cw_col[tid] = (float)cnt[colBase + tid];
  }

  const int lane = tid & 63;
  const int wid  = tid >> 6;        // 4 waves, 2x2 grid of 64x64 wave tiles
  const int wr   = wid >> 1;
  const int wc   = wid & 1;
  const int l15  = lane & 15;
  const int kb   = lane >> 4;       // k-octet selector 0..3

  // staging geometry: 512 16B-chunks per 128x32 tile; wave w issues chunks
  // (2w+cc)*64+lane; global source pre-swizzled with involution slot^=(row>>1)&3
  const int ch0 = (wid * 2 + 0) * 64 + lane;
  const int ch1 = (wid * 2 + 1) * 64 + lane;
  const int r0 = ch0 >> 2, kq0 = (ch0 & 3) ^ ((ch0 >> 3) & 3);
  const int r1 = ch1 >> 2, kq1 = (ch1 & 3) ^ ((ch1 >> 3) & 3);
  const ushort* gA0 = fb + (size_t)(rowBase + r0) * d + kq0 * 8;
  const ushort* gA1 = fb + (size_t)(rowBase + r1) * d + kq1 * 8;
  const ushort* gB0 = fb + (size_t)(colBase + r0) * d + kq0 * 8;
  const ushort* gB1 = fb + (size_t)(colBase + r1) * d + kq1 * 8;
  const int lo0 = (wid * 2 + 0) * 512;
  const int lo1 = (wid * 2 + 1) * 512;

  f32x4 acc[4][4] = {};

  // swizzled ds_read offsets (ushort units): row*32 + (kb ^ ((row>>1)&3))*8
  int aoff[4], boff[4];
#pragma unroll
  for (int m = 0; m < 4; ++m) {
    int row = wr * 64 + m * 16 + l15;
    aoff[m] = row * 32 + ((kb ^ ((row >> 1) & 3)) * 8);
  }
#pragma unroll
  for (int nf = 0; nf < 4; ++nf) {
    int row = wc * 64 + nf * 16 + l15;
    boff[nf] = row * 32 + ((kb ^ ((row >> 1) & 3)) * 8);
  }

  // drain metadata loads so manual vmcnt counts are exact (in-order retire)
  asm volatile("s_waitcnt vmcnt(0) lgkmcnt(0)" ::: "memory");

  // prologue: stage tiles 0 and 1 (8 loads in flight)
  async_load16(gA0, &Als[0][lo0]);
  async_load16(gA1, &Als[0][lo1]);
  async_load16(gB0, &Bls[0][lo0]);
  async_load16(gB1, &Bls[0][lo1]);
  const int nk = d / BK;
  if (nk > 1) {
    async_load16(gA0 + BK, &Als[1][lo0]);
    async_load16(gA1 + BK, &Als[1][lo1]);
    async_load16(gB0 + BK, &Bls[1][lo0]);
    async_load16(gB1 + BK, &Bls[1][lo1]);
  }

  int cur = 0;
  for (int t = 0; t < nk; ++t) {
    // tile t landed when ≤4 (tile t+1's) loads remain outstanding
    if (t == nk - 1) asm volatile("s_waitcnt vmcnt(0)" ::: "memory");
    else             asm volatile("s_waitcnt vmcnt(4)" ::: "memory");
    asm volatile("s_barrier" ::: "memory");   // memory clobber: no ds motion across

    // issue tile t+2 into ring slot (cur+2)%3 — its readers passed the barrier
    if (t + 2 < nk) {
      int nxt = cur + 2; if (nxt >= 3) nxt -= 3;
      int ko = (t + 2) * BK;
      async_load16(gA0 + ko, &Als[nxt][lo0]);
      async_load16(gA1 + ko, &Als[nxt][lo1]);
      async_load16(gB0 + ko, &Bls[nxt][lo0]);
      async_load16(gB1 + ko, &Bls[nxt][lo1]);
    }

    short8 afr[4], bfr[4];
#pragma unroll
    for (int m = 0; m < 4; ++m)
      afr[m] = *reinterpret_cast<const short8*>(&Als[cur][aoff[m]]);
#pragma unroll
    for (int nf = 0; nf < 4; ++nf)
      bfr[nf] = *reinterpret_cast<const short8*>(&Bls[cur][boff[nf]]);
    // no manual lgkmcnt: data-deps give compiler-scheduled fine-grained waits

    // swapped operands: acc[m][nf] row = rowBase+wr*64+m*16+l15 (lane-fixed),
    // col = colBase+wc*64+nf*16+kb*4+q
#pragma unroll
    for (int m = 0; m < 4; ++m)
#pragma unroll
      for (int nf = 0; nf < 4; ++nf)
        acc[m][nf] = __builtin_amdgcn_mfma_f32_16x16x32_bf16(bfr[nf], afr[m], acc[m][nf], 0, 0, 0);

    cur = (cur + 1 == 3) ? 0 : cur + 1;
  }

  // ---- epilogue: per-lane masked fold -> block scalar ----
  const float beta = 1.0f - alpha;
  int tc_r[4][4]; float cw_r[4][4];
#pragma unroll
  for (int nf = 0; nf < 4; ++nf)
#pragma unroll
    for (int q = 0; q < 4; ++q) {
      int cl = wc * 64 + nf * 16 + kb * 4 + q;
      tc_r[nf][q] = t_col[cl];
      cw_r[nf][q] = cw_col[cl];
    }

  const int  stale_row = n_new - 1;
  const bool blk_stale = (stale_row >= rowBase) && (stale_row < rowBase + BM);
  const int  srl = stale_row - rowBase;

  float c = 0.f;
#pragma unroll
  for (int m = 0; m < 4; ++m) {
    int rl = wr * 64 + m * 16 + l15;
    int r  = rowBase + rl;
    int tr = t_row[rl];
    bool isnew = (r < n_new);
    float p = 0.f, ng = 0.f;
#pragma unroll
    for (int nf = 0; nf < 4; ++nf)
#pragma unroll
      for (int q = 0; q < 4; ++q) {
        float s = acc[m][nf][q];
        bool same = (tr == tc_r[nf][q]);
        if (isnew) {
          if (same && s < POS_THR)  p  += cw_r[nf][q] * (1.0f - s);
          if (!same && s > MARGIN)  ng += s;
        } else {
          if (!same && s > MARGIN)  ng += cw_r[nf][q] * s;
        }
      }
    // stale row: full cross-lane sum of its pos partial (wave-uniform branch)
    if (blk_stale && wr == (srl >> 6) && m == ((srl >> 4) & 3)) {
      float pr = p;
      pr += __shfl_xor(pr, 16); pr += __shfl_xor(pr, 32);
      if (lane < 16 && rl == srl) atomicAdd(&misc[NSLOTS], pr);
    }
    c += isnew ? fmaf(alpha, p, beta * ng) : beta * ng;
  }
  // wave reduce -> block reduce -> one atomic per block into 256 slots
#pragma unroll
  for (int off = 32; off; off >>= 1) c += __shfl_xor(c, off);
  if (lane == 0) red[wid] = c;
  __syncthreads();
  if (tid == 0)
    atomicAdd(&misc[(blockIdx.y * gridDim.x + blockIdx.x) & (NSLOTS - 1)],
              red[0] + red[1] + red[2] + red[3]);
}

// ---------- finalize: 64 threads, read 257 floats ----------
__global__ void finalize_kernel(const float* __restrict__ misc,
                                float* __restrict__ out, int n, int n_new,
                                float alpha) {
  int t = threadIdx.x;
  float c = misc[t] + misc[t + 64] + misc[t + 128] + misc[t + 192];
#pragma unroll
  for (int off = 32; off; off >>= 1) c += __shfl_xor(c, off);
  if (t == 0)
    out[0] = (c + (float)(n - n_new) * alpha * misc[NSLOTS]) / (float)n;
}

// ---------- launch ----------
extern "C" void kernel_launch(void* const* d_in, const int* in_sizes, int n_in,
                              void* d_out, int out_size, void* d_ws, size_t ws_size,
                              hipStream_t stream) {
  const float* feature = (const float*)d_in[0];
  const int*   target  = (const int*)d_in[1];
  const int*   new_idx = (const int*)d_in[2];

  const int n     = in_sizes[1];
  const int d     = in_sizes[0] / n;
  const int n_new = in_sizes[2];
  const int n_old = (n_in > 3) ? in_sizes[3] : 0;
  const float alpha = (n_old != 0) ? 0.9f : 0.5f;
  const int npanel = n / BN;

  auto al = [](size_t x) { return (x + 255) & ~(size_t)255; };
  char* ws = (char*)d_ws;
  ushort* fb    = (ushort*)ws;
  size_t  off   = al((size_t)n * d * sizeof(ushort));
  int*    cnt   = (int*)(ws + off);   off += al((size_t)n * sizeof(int));
  int*    flags = (int*)(ws + off);   off += al((size_t)npanel * sizeof(int));
  float*  misc  = (float*)(ws + off); // NSLOTS partials + [NSLOTS]=stale

  int total8 = (n * d) / 8;
  prep_kernel<<<(total8 + 255) / 256, 256, 0, stream>>>(feature, fb, cnt, flags,
                                                        misc, total8, n, npanel);
  count_kernel<<<(n_new + 255) / 256, 256, 0, stream>>>(new_idx, cnt, flags, n_new);

  dim3 grid(n / BN, n / BM);
  simloss_kernel<<<grid, 256, 0, stream>>>(fb, target, cnt, flags, misc,
                                           d, n_new, alpha);

  finalize_kernel<<<1, 64, 0, stream>>>(misc, (float*)d_out, n, n_new, alpha);
}